// Round 9
// baseline (218.573 us; speedup 1.0000x reference)
//
#include <hip/hip_runtime.h>

#define F 64
#define F3 192
#define XMW 384   // fused bf16 table row: 768B = 512B region A (ushort4/lane) + 256B region B (uint/lane)
#define NS 8      // j-slices == XCDs; bf16 window = 2500 atoms * 768B = 1.9MB << 4MB per-XCD L2

typedef unsigned short ushort_t;
typedef unsigned int   u32;
typedef ushort_t us4 __attribute__((ext_vector_type(4)));

__device__ __forceinline__ float bf2f(ushort_t u) {
    return __uint_as_float((unsigned)u << 16);
}
__device__ __forceinline__ ushort_t f2bf(float v) {   // round-to-nearest-even
    unsigned b = __float_as_uint(v);
    return (ushort_t)((b + 0x7FFFu + ((b >> 16) & 1u)) >> 16);
}

// ---------------- Kernel 1: per-atom MLP + packed bf16 table build ----------------
__global__ __launch_bounds__(256) void mlp_kernel(
    const float* __restrict__ q, const float* __restrict__ mu,
    const float* __restrict__ W1, const float* __restrict__ b1,
    const float* __restrict__ W2, const float* __restrict__ b2,
    ushort_t* __restrict__ xmu, int N)
{
    __shared__ float W2s[F * F3];   // 48 KB
    __shared__ float b1s[F];
    __shared__ float b2s[F3];
    __shared__ float qs[4 * F];
    __shared__ float hs[4 * F];

    const int t = threadIdx.x;
    for (int i = t; i < F * F3; i += 256) W2s[i] = W2[i];
    if (t < F)  b1s[t] = b1[t];
    if (t < F3) b2s[t] = b2[t];
    __syncthreads();

    const int a = t >> 6;
    const int f = t & 63;
    const int ngroups = (N + 3) >> 2;

    for (int g = blockIdx.x; g < ngroups; g += gridDim.x) {
        const int atom = g * 4 + a;
        qs[t] = (atom < N) ? q[atom * F + f] : 0.f;
        __syncthreads();

        float h = b1s[f];
        #pragma unroll
        for (int k = 0; k < F; ++k)
            h = fmaf(qs[a * F + k], W1[k * F + f], h);
        h = h / (1.f + __expf(-h));   // SiLU
        hs[t] = h;
        __syncthreads();

        float acc0 = b2s[f], acc1 = b2s[F + f], acc2 = b2s[2 * F + f];
        #pragma unroll
        for (int k = 0; k < F; ++k) {
            const float hk = hs[a * F + k];
            acc0 = fmaf(hk, W2s[k * F3 + f],         acc0);
            acc1 = fmaf(hk, W2s[k * F3 + F + f],     acc1);
            acc2 = fmaf(hk, W2s[k * F3 + 2 * F + f], acc2);
        }
        if (atom < N) {
            ushort_t* r = xmu + (size_t)atom * XMW;
            const float* mi = mu + (size_t)atom * F3;
            us4 va;
            va.x = f2bf(acc0);
            va.y = f2bf(acc1);
            va.z = f2bf(acc2);
            va.w = f2bf(mi[f]);
            ((us4*)r)[f] = va;
            const u32 ub = (u32)f2bf(mi[F + f]) | ((u32)f2bf(mi[2 * F + f]) << 16);
            ((u32*)(r + 256))[f] = ub;
        }
        __syncthreads();
    }
}

// ---------------- Kernel 2: CSR row starts from sorted idx_i ----------------
__global__ void rowstart_kernel(const int* __restrict__ idx_i,
                                int* __restrict__ row_start, int P, int N)
{
    const int p = blockIdx.x * blockDim.x + threadIdx.x;
    if (p > P) return;
    if (p == P) {
        const int prev = idx_i[P - 1];
        for (int n = prev + 1; n <= N; ++n) row_start[n] = P;
    } else {
        const int cur  = idx_i[p];
        const int prev = (p == 0) ? -1 : idx_i[p - 1];
        for (int n = prev + 1; n <= cur; ++n) row_start[n] = p;
    }
}

// ---------------- Kernel 3: per-atom count-sort of pairs by j-slice ----------------
__global__ __launch_bounds__(64) void bucket_kernel(
    const int* __restrict__ idx_j, const int* __restrict__ row_start,
    int* __restrict__ ord, int* __restrict__ cs, int N)
{
    __shared__ int soff[64][NS + 1];
    const int t = threadIdx.x;
    const int a = blockIdx.x * 64 + t;
    if (a >= N) return;
    const int s0 = row_start[a], s1 = row_start[a + 1];

    for (int s = 0; s < NS; ++s) soff[t][s] = 0;
    for (int p = s0; p < s1; ++p) {
        const int j = idx_j[p];
        const int s = (int)(((long long)j * NS) / N);
        soff[t][s]++;
    }
    int off = s0;
    for (int s = 0; s < NS; ++s) {
        const int c = soff[t][s];
        cs[a * (NS + 1) + s] = off;
        soff[t][s] = off;          // becomes running cursor
        off += c;
    }
    cs[a * (NS + 1) + NS] = off;   // == s1
    for (int p = s0; p < s1; ++p) {
        const int j = idx_j[p];
        const int s = (int)(((long long)j * NS) / N);
        ord[soff[t][s]++] = p;
    }
}

// ---------------- Kernel 4: sliced accumulation -> bf16 partials ----------------
// Grid = ngroups*NS; slice = blockIdx&7 -> round-robin pins each slice to one XCD,
// whose 1.9MB xmu window stays L2-resident. Block = 4 waves = 4 atoms (same slice).
// Lane f: {dq[f], dmu[0..2][f]} accumulated fp32, stored as one us4 bf16 NT store.
__global__ __launch_bounds__(256) void slice_accum_kernel(
    const float* __restrict__ Wij, const float* __restrict__ dir_ij,
    const int* __restrict__ idx_j, const int* __restrict__ ord,
    const int* __restrict__ cs, const ushort_t* __restrict__ xmu,
    ushort_t* __restrict__ partial, int N)
{
    const int s = blockIdx.x & (NS - 1);
    const int g = blockIdx.x >> 3;
    const int a = g * 4 + (threadIdx.x >> 6);
    const int f = threadIdx.x & 63;
    if (a >= N) return;

    const int p0 = __builtin_amdgcn_readfirstlane(cs[a * (NS + 1) + s]);
    const int p1 = __builtin_amdgcn_readfirstlane(cs[a * (NS + 1) + s + 1]);

    float dq = 0.f, dm0 = 0.f, dm1 = 0.f, dm2 = 0.f;

    #pragma unroll 2
    for (int pp = p0; pp < p1; ++pp) {
        const int p = __builtin_amdgcn_readfirstlane(ord[pp]);
        const int j = __builtin_amdgcn_readfirstlane(idx_j[p]);

        const float*    wp = Wij + (size_t)p * F3;
        const ushort_t* r  = xmu + (size_t)j * XMW;

        const float wq = __builtin_nontemporal_load(wp + f);
        const float wr = __builtin_nontemporal_load(wp + F + f);
        const float wm = __builtin_nontemporal_load(wp + 2 * F + f);

        const us4 va = ((const us4*)r)[f];          // {x0,x1,x2,m0}
        const u32 ub = ((const u32*)(r + 256))[f];  // {m1,m2}

        const float xq = bf2f(va.x);
        const float xr = bf2f(va.y);
        const float xm = bf2f(va.z);
        const float m0 = bf2f(va.w);
        const float m1 = bf2f((ushort_t)(ub & 0xFFFFu));
        const float m2 = bf2f((ushort_t)(ub >> 16));

        const float d0 = dir_ij[p * 3 + 0];
        const float d1 = dir_ij[p * 3 + 1];
        const float d2 = dir_ij[p * 3 + 2];

        dq = fmaf(wq, xq, dq);
        const float vr = wr * xr;
        const float vm = wm * xm;
        dm0 = fmaf(vr, d0, fmaf(vm, m0, dm0));
        dm1 = fmaf(vr, d1, fmaf(vm, m1, dm1));
        dm2 = fmaf(vr, d2, fmaf(vm, m2, dm2));
    }

    us4 v;
    v.x = f2bf(dq);
    v.y = f2bf(dm0);
    v.z = f2bf(dm1);
    v.w = f2bf(dm2);
    ushort_t* pr = partial + ((size_t)s * N + a) * 256;   // 256 ushorts per (s,atom)
    __builtin_nontemporal_store(v, (us4*)pr + f);
}

// ---------------- Kernel 5: reduce bf16 partials + base -> out ----------------
__global__ __launch_bounds__(256) void reduce_kernel(
    const float* __restrict__ q, const float* __restrict__ mu,
    const ushort_t* __restrict__ partial, float* __restrict__ out, int N)
{
    const int a = blockIdx.x * 4 + (threadIdx.x >> 6);
    const int f = threadIdx.x & 63;
    if (a >= N) return;

    float dq = 0.f, dm0 = 0.f, dm1 = 0.f, dm2 = 0.f;
    #pragma unroll
    for (int s = 0; s < NS; ++s) {
        const us4 v = __builtin_nontemporal_load(
            (const us4*)(partial + ((size_t)s * N + a) * 256) + f);
        dq  += bf2f(v.x);
        dm0 += bf2f(v.y);
        dm1 += bf2f(v.z);
        dm2 += bf2f(v.w);
    }

    out[(size_t)a * F + f] = q[(size_t)a * F + f] + dq;
    float*       om = out + (size_t)N * F + (size_t)a * F3;
    const float* mi = mu  + (size_t)a * F3;
    om[f]         = mi[f]         + dm0;
    om[F + f]     = mi[F + f]     + dm1;
    om[2 * F + f] = mi[2 * F + f] + dm2;
}

extern "C" void kernel_launch(void* const* d_in, const int* in_sizes, int n_in,
                              void* d_out, int out_size, void* d_ws, size_t ws_size,
                              hipStream_t stream)
{
    const float* q      = (const float*)d_in[0];
    const float* mu     = (const float*)d_in[1];
    const float* Wij    = (const float*)d_in[2];
    const float* dir_ij = (const float*)d_in[3];
    const int*   idx_i  = (const int*)d_in[4];
    const int*   idx_j  = (const int*)d_in[5];
    const float* W1     = (const float*)d_in[7];
    const float* b1     = (const float*)d_in[8];
    const float* W2     = (const float*)d_in[9];
    const float* b2     = (const float*)d_in[10];

    const int N = in_sizes[0] / F;        // 20000
    const int P = in_sizes[2] / F3;       // 640000

    char* w = (char*)d_ws;
    size_t o = 0;
    ushort_t* xmu = (ushort_t*)(w + o);    o += (size_t)N * XMW * sizeof(ushort_t);
    o = (o + 255) & ~(size_t)255;
    int* row_start = (int*)(w + o);        o += (size_t)(N + 1) * sizeof(int);
    o = (o + 255) & ~(size_t)255;
    int* ord = (int*)(w + o);              o += (size_t)P * sizeof(int);
    o = (o + 255) & ~(size_t)255;
    int* cs = (int*)(w + o);               o += (size_t)N * (NS + 1) * sizeof(int);
    o = (o + 255) & ~(size_t)255;
    ushort_t* partial = (ushort_t*)(w + o); o += (size_t)NS * N * 256 * sizeof(ushort_t);

    float* out = (float*)d_out;
    const int ngroups = (N + 3) / 4;

    mlp_kernel<<<1280, 256, 0, stream>>>(q, mu, W1, b1, W2, b2, xmu, N);
    rowstart_kernel<<<(P + 1 + 255) / 256, 256, 0, stream>>>(idx_i, row_start, P, N);
    bucket_kernel<<<(N + 63) / 64, 64, 0, stream>>>(idx_j, row_start, ord, cs, N);
    slice_accum_kernel<<<ngroups * NS, 256, 0, stream>>>(Wij, dir_ij, idx_j, ord,
                                                         cs, xmu, partial, N);
    reduce_kernel<<<ngroups, 256, 0, stream>>>(q, mu, partial, out, N);
}

// Round 10
// 180.904 us; speedup vs baseline: 1.2082x; 1.2082x over previous
//
#include <hip/hip_runtime.h>

#define F 64
#define F3 192
#define XMW 384   // fused bf16 table row: 768B = 512B region A (ushort4/lane) + 256B region B (uint/lane)
#define MLP_BLOCKS 1280   // fused kernel: blocks [0,MLP_BLOCKS) do MLP, rest do rowstart

typedef unsigned short ushort_t;
typedef unsigned int   u32;
typedef ushort_t us4 __attribute__((ext_vector_type(4)));

__device__ __forceinline__ float bf2f(ushort_t u) {
    return __uint_as_float((unsigned)u << 16);
}
__device__ __forceinline__ ushort_t f2bf(float v) {   // round-to-nearest-even
    unsigned b = __float_as_uint(v);
    return (ushort_t)((b + 0x7FFFu + ((b >> 16) & 1u)) >> 16);
}

// ---------------- Kernel 1 (fused): per-atom MLP + bf16 table build | CSR rowstart ----
// Blocks [0, MLP_BLOCKS): x = silu(q@W1+b1)@W2+b2, packed with bf16(mu) into xmu.
// Blocks [MLP_BLOCKS, ...): row_start[] scan over sorted idx_i (independent work,
// fused to save a launch and overlap with the MLP's memory phase).
__global__ __launch_bounds__(256) void mlp_rowstart_kernel(
    const float* __restrict__ q, const float* __restrict__ mu,
    const float* __restrict__ W1, const float* __restrict__ b1,
    const float* __restrict__ W2, const float* __restrict__ b2,
    ushort_t* __restrict__ xmu,
    const int* __restrict__ idx_i, int* __restrict__ row_start, int P, int N)
{
    if (blockIdx.x >= MLP_BLOCKS) {
        // ---- rowstart part ----
        const int p = (blockIdx.x - MLP_BLOCKS) * 256 + threadIdx.x;
        if (p > P) return;
        if (p == P) {
            const int prev = idx_i[P - 1];
            for (int n = prev + 1; n <= N; ++n) row_start[n] = P;
        } else {
            const int cur  = idx_i[p];
            const int prev = (p == 0) ? -1 : idx_i[p - 1];
            for (int n = prev + 1; n <= cur; ++n) row_start[n] = p;
        }
        return;
    }

    // ---- MLP part ----
    __shared__ float W2s[F * F3];   // 48 KB
    __shared__ float b1s[F];
    __shared__ float b2s[F3];
    __shared__ float qs[4 * F];
    __shared__ float hs[4 * F];

    const int t = threadIdx.x;
    for (int i = t; i < F * F3; i += 256) W2s[i] = W2[i];
    if (t < F)  b1s[t] = b1[t];
    if (t < F3) b2s[t] = b2[t];
    __syncthreads();

    const int a = t >> 6;
    const int f = t & 63;
    const int ngroups = (N + 3) >> 2;

    for (int g = blockIdx.x; g < ngroups; g += MLP_BLOCKS) {
        const int atom = g * 4 + a;
        qs[t] = (atom < N) ? q[atom * F + f] : 0.f;
        __syncthreads();

        float h = b1s[f];
        #pragma unroll
        for (int k = 0; k < F; ++k)
            h = fmaf(qs[a * F + k], W1[k * F + f], h);
        h = h / (1.f + __expf(-h));   // SiLU
        hs[t] = h;
        __syncthreads();

        float acc0 = b2s[f], acc1 = b2s[F + f], acc2 = b2s[2 * F + f];
        #pragma unroll
        for (int k = 0; k < F; ++k) {
            const float hk = hs[a * F + k];
            acc0 = fmaf(hk, W2s[k * F3 + f],         acc0);
            acc1 = fmaf(hk, W2s[k * F3 + F + f],     acc1);
            acc2 = fmaf(hk, W2s[k * F3 + 2 * F + f], acc2);
        }
        if (atom < N) {
            ushort_t* r = xmu + (size_t)atom * XMW;
            const float* mi = mu + (size_t)atom * F3;
            us4 va;
            va.x = f2bf(acc0);
            va.y = f2bf(acc1);
            va.z = f2bf(acc2);
            va.w = f2bf(mi[f]);
            ((us4*)r)[f] = va;
            const u32 ub = (u32)f2bf(mi[F + f]) | ((u32)f2bf(mi[2 * F + f]) << 16);
            ((u32*)(r + 256))[f] = ub;
        }
        __syncthreads();
    }
}

// ---------------- Kernel 2: per-atom accumulation, 1 wave per atom ----------------
// Lane f owns channels {dq[f], dmu[0..2][f]}. Per pair: 3 NT fp32 Wij dword loads
// (full-width 256B) + 1 dwordx2 + 1 dword packed-bf16 gather (768B total/pair)
// + wave-uniform scalar loads for j and dir_ij. Direct out write; no atomics
// (CSR from sorted idx_i).
__global__ __launch_bounds__(256) void accum_kernel(
    const float* __restrict__ q, const float* __restrict__ mu,
    const float* __restrict__ Wij, const float* __restrict__ dir_ij,
    const int* __restrict__ idx_j, const int* __restrict__ row_start,
    const ushort_t* __restrict__ xmu, float* __restrict__ out, int N)
{
    const int a = blockIdx.x * 4 + (threadIdx.x >> 6);
    const int f = threadIdx.x & 63;
    if (a >= N) return;

    const int start = __builtin_amdgcn_readfirstlane(row_start[a]);
    const int end   = __builtin_amdgcn_readfirstlane(row_start[a + 1]);

    float dq = 0.f, dm0 = 0.f, dm1 = 0.f, dm2 = 0.f;

    #pragma unroll 4
    for (int p = start; p < end; ++p) {
        const int j = __builtin_amdgcn_readfirstlane(idx_j[p]);

        const float*    wp = Wij + (size_t)p * F3;
        const ushort_t* r  = xmu + (size_t)j * XMW;

        const float wq = __builtin_nontemporal_load(wp + f);
        const float wr = __builtin_nontemporal_load(wp + F + f);
        const float wm = __builtin_nontemporal_load(wp + 2 * F + f);

        const us4 va = ((const us4*)r)[f];          // {x0,x1,x2,m0}
        const u32 ub = ((const u32*)(r + 256))[f];  // {m1,m2}

        const float xq = bf2f(va.x);
        const float xr = bf2f(va.y);
        const float xm = bf2f(va.z);
        const float m0 = bf2f(va.w);
        const float m1 = bf2f((ushort_t)(ub & 0xFFFFu));
        const float m2 = bf2f((ushort_t)(ub >> 16));

        const float d0 = dir_ij[p * 3 + 0];
        const float d1 = dir_ij[p * 3 + 1];
        const float d2 = dir_ij[p * 3 + 2];

        dq = fmaf(wq, xq, dq);
        const float vr = wr * xr;
        const float vm = wm * xm;
        dm0 = fmaf(vr, d0, fmaf(vm, m0, dm0));
        dm1 = fmaf(vr, d1, fmaf(vm, m1, dm1));
        dm2 = fmaf(vr, d2, fmaf(vm, m2, dm2));
    }

    out[(size_t)a * F + f] = __builtin_nontemporal_load(q + (size_t)a * F + f) + dq;
    float*       om = out + (size_t)N * F + (size_t)a * F3;
    const float* mi = mu  + (size_t)a * F3;
    om[f]         = __builtin_nontemporal_load(mi + f)         + dm0;
    om[F + f]     = __builtin_nontemporal_load(mi + F + f)     + dm1;
    om[2 * F + f] = __builtin_nontemporal_load(mi + 2 * F + f) + dm2;
}

extern "C" void kernel_launch(void* const* d_in, const int* in_sizes, int n_in,
                              void* d_out, int out_size, void* d_ws, size_t ws_size,
                              hipStream_t stream)
{
    const float* q      = (const float*)d_in[0];
    const float* mu     = (const float*)d_in[1];
    const float* Wij    = (const float*)d_in[2];
    const float* dir_ij = (const float*)d_in[3];
    const int*   idx_i  = (const int*)d_in[4];
    const int*   idx_j  = (const int*)d_in[5];
    const float* W1     = (const float*)d_in[7];
    const float* b1     = (const float*)d_in[8];
    const float* W2     = (const float*)d_in[9];
    const float* b2     = (const float*)d_in[10];

    const int N = in_sizes[0] / F;        // 20000
    const int P = in_sizes[2] / F3;       // 640000

    char* w = (char*)d_ws;
    size_t o = 0;
    ushort_t* xmu = (ushort_t*)(w + o);    o += (size_t)N * XMW * sizeof(ushort_t);
    o = (o + 255) & ~(size_t)255;
    int* row_start = (int*)(w + o);        o += (size_t)(N + 1) * sizeof(int);

    float* out = (float*)d_out;

    const int rs_blocks = (P + 1 + 255) / 256;
    mlp_rowstart_kernel<<<MLP_BLOCKS + rs_blocks, 256, 0, stream>>>(
        q, mu, W1, b1, W2, b2, xmu, idx_i, row_start, P, N);
    accum_kernel<<<(N + 3) / 4, 256, 0, stream>>>(q, mu, Wij, dir_ij, idx_j,
                                                  row_start, xmu, out, N);
}